// Round 2
// baseline (5890.747 us; speedup 1.0000x reference)
//
#include <hip/hip_runtime.h>
#include <hip/hip_bf16.h>
#include <stdint.h>

#define HIDDEN 1024
#define FEAT   512
#define PREV   10
#define PRED   20
#define BATCH  1024
#define KTOT   (HIDDEN + FEAT)   // 1536
#define N4H    4096
#define TSTEPS (PREV + PRED)     // 30
#define NBLK   1024              // persistent grid: 4 blocks/CU on 256 CUs

typedef __attribute__((ext_vector_type(8))) short short8;
typedef __attribute__((ext_vector_type(4))) float f32x4;

// ---- async global->LDS 16B copy (wave-uniform LDS base + lane*16) ----
typedef __attribute__((address_space(3))) unsigned int u32_lds;
typedef const __attribute__((address_space(1))) unsigned int u32_gbl;

__device__ __forceinline__ void async16(void* lds, const void* g) {
  u32_lds* lp = (u32_lds*)(unsigned int)(uintptr_t)lds;
  u32_gbl* gp = (u32_gbl*)(uintptr_t)g;
  __builtin_amdgcn_global_load_lds(gp, lp, 16, 0, 0);
}

__device__ __forceinline__ float sigmoidf_(float x) {
  return 1.0f / (1.0f + __expf(-x));
}
__device__ __forceinline__ float tanhf_(float x) {
  return 1.0f - 2.0f / (1.0f + __expf(2.0f * x));
}

// ---- pack [Wh;Wx] (fp32, [K,4096] gate-blocked) -> WpT (bf16, [4096,K], gate-interleaved n=4j+g) ----
__global__ void pack_w_kernel(const float* __restrict__ Wx, const float* __restrict__ Wh,
                              __hip_bfloat16* __restrict__ WpT) {
  __shared__ float tile[64][65];
  const int k0 = blockIdx.x * 64, n0 = blockIdx.y * 64;
  const int tid = threadIdx.x;
  const float* src = (k0 < HIDDEN) ? (Wh + (size_t)k0 * N4H) : (Wx + (size_t)(k0 - HIDDEN) * N4H);
  {
    const int jl = tid & 15, g = (tid >> 4) & 3, klb = tid >> 6;
#pragma unroll
    for (int it = 0; it < 16; ++it) {
      int kl = klb + it * 4;
      tile[kl][4 * jl + g] = src[(size_t)kl * N4H + g * HIDDEN + (n0 >> 2) + jl];
    }
  }
  __syncthreads();
  {
    const int kl = tid & 63, nlb = tid >> 6;
#pragma unroll
    for (int it = 0; it < 16; ++it) {
      int nl = nlb + it * 4;
      WpT[(size_t)(n0 + nl) * KTOT + k0 + kl] = __float2bfloat16(tile[kl][nl]);
    }
  }
}

__global__ void pack_bias_kernel(const float* __restrict__ b, float* __restrict__ bp) {
  int n = blockIdx.x * 256 + threadIdx.x;
  if (n < N4H) bp[n] = b[(n & 3) * HIDDEN + (n >> 2)];
}

// ---- convert inputs fp32 -> bf16 ----
__global__ void cvt_x_kernel(const float* __restrict__ xr, const float* __restrict__ xf,
                             __hip_bfloat16* __restrict__ xrb, __hip_bfloat16* __restrict__ xfb) {
  const int NR4 = BATCH * TSTEPS * FEAT / 4;
  const int NF4 = BATCH * PRED * FEAT / 4;
  int i = blockIdx.x * 256 + threadIdx.x;
  float4 v;
  __hip_bfloat16* dst;
  if (i < NR4) {
    v = ((const float4*)xr)[i];
    dst = xrb + (size_t)i * 4;
  } else {
    int j = i - NR4;
    if (j >= NF4) return;
    v = ((const float4*)xf)[j];
    dst = xfb + (size_t)j * 4;
  }
  dst[0] = __float2bfloat16(v.x);
  dst[1] = __float2bfloat16(v.y);
  dst[2] = __float2bfloat16(v.z);
  dst[3] = __float2bfloat16(v.w);
}

// ---- persistent LSTM: all 30 steps in one cooperative dispatch ----
// grid 1024 blocks x 256 thr. Block bid: n-tile nt = bid&31 (128 cols, fixed all
// steps -> B-slice L2-resident), row-tile rt = bid>>5 (64 batch rows). fp32 cell
// state c lives in LDS for the whole sequence. Grid barrier between steps.
__global__ __launch_bounds__(256, 4)
void lstm_persistent(const __hip_bfloat16* __restrict__ xrb,
                     const __hip_bfloat16* __restrict__ xfb,
                     const __hip_bfloat16* __restrict__ WpT,
                     const float* __restrict__ biasp,
                     const float* __restrict__ w2,
                     __hip_bfloat16* __restrict__ hb0,
                     __hip_bfloat16* __restrict__ hb1,
                     float* __restrict__ cbuf,
                     float* __restrict__ accout,
                     unsigned* __restrict__ bar) {
  __shared__ __align__(16) char smem[24576];  // A stage 8K | B stage 16K ; z-epilogue overlays (64x68 f32)
  __shared__ float cl[64 * 33];               // cell state, stride 33 vs bank conflicts
  char* smA = smem;
  char* smB = smem + 8192;

  const int tid = threadIdx.x;
  const int bid = blockIdx.x;
  const int nt = bid & 31, rt = bid >> 5;
  const int n0 = nt * 128;
  const int r0 = rt * 64;
  const int w = tid >> 6, l = tid & 63;
  const int sub = l >> 3;
  const int csrc = (l & 7) ^ sub;   // XOR-swizzled 16B source column
  const int quad = l >> 4, lrow = l & 15;
  const int jbase = nt * 32;
  unsigned* cnt = bar;
  unsigned* flag = bar + 32;        // separate cache line

  const __hip_bfloat16* bbase0 = WpT + (size_t)n0 * KTOT;

  if (rt < 16) {  // prefix-active blocks start with zero cell state
    for (int i = tid; i < 2048; i += 256) cl[(i >> 5) * 33 + (i & 31)] = 0.f;
  }

#pragma unroll 1
  for (int t = 0; t < TSTEPS; ++t) {
    const __hip_bfloat16* hcur = (t & 1) ? hb1 : hb0;
    __hip_bfloat16* hnext = (t & 1) ? hb0 : hb1;
    const bool active = (t >= PREV) || (rt < 16);

    if (t == PREV && rt >= 16) {
      // fork: fake-half blocks pick up cell state written by prefix owners at t=9
      for (int i = tid; i < 2048; i += 256)
        cl[(i >> 5) * 33 + (i & 31)] = cbuf[(size_t)(r0 + (i >> 5)) * HIDDEN + jbase + (i & 31)];
    }

    if (active) {
      f32x4 acc[4][2];
#pragma unroll
      for (int a = 0; a < 4; ++a)
#pragma unroll
        for (int b_ = 0; b_ < 2; ++b_) acc[a][b_] = (f32x4){0.f, 0.f, 0.f, 0.f};

#pragma unroll 1
      for (int kt = 0; kt < KTOT / 64; ++kt) {
        const int k0 = kt * 64;
        const __hip_bfloat16* abase;
        int astr;
        if (k0 < HIDDEN) {
          abase = hcur + (size_t)r0 * HIDDEN + k0;
          astr = HIDDEN;
        } else if (r0 < BATCH) {
          abase = xrb + ((size_t)r0 * TSTEPS + t) * FEAT + (k0 - HIDDEN);
          astr = TSTEPS * FEAT;
        } else {
          abase = xfb + ((size_t)(r0 - BATCH) * PRED + (t - PREV)) * FEAT + (k0 - HIDDEN);
          astr = PRED * FEAT;
        }
#pragma unroll
        for (int it = 0; it < 2; ++it)
          async16(smA + (it * 32 + w * 8) * 128,
                  abase + (size_t)(it * 32 + w * 8 + sub) * astr + csrc * 8);
        const __hip_bfloat16* bb = bbase0 + k0;
#pragma unroll
        for (int it = 0; it < 4; ++it)
          async16(smB + (it * 32 + w * 8) * 128,
                  bb + (size_t)(it * 32 + w * 8 + sub) * KTOT + csrc * 8);
        __syncthreads();
#pragma unroll
        for (int kk = 0; kk < 2; ++kk) {
          const int swz = (((kk << 2) + quad) ^ (lrow & 7)) * 16;
          short8 af[4], bf[2];
#pragma unroll
          for (int mi = 0; mi < 4; ++mi)
            af[mi] = *(const short8*)(smA + (mi * 16 + lrow) * 128 + swz);
#pragma unroll
          for (int ni = 0; ni < 2; ++ni)
            bf[ni] = *(const short8*)(smB + (w * 32 + ni * 16 + lrow) * 128 + swz);
#pragma unroll
          for (int mi = 0; mi < 4; ++mi)
#pragma unroll
            for (int ni = 0; ni < 2; ++ni)
              acc[mi][ni] = __builtin_amdgcn_mfma_f32_16x16x32_bf16(af[mi], bf[ni], acc[mi][ni], 0, 0, 0);
        }
        __syncthreads();
      }

      // ---- epilogue in two 64-col halves (z overlays staging LDS, stride 68) ----
      float* zb = (float*)smem;
      const int kout = t - PREV;
#pragma unroll 1
      for (int h2 = 0; h2 < 2; ++h2) {
        if ((w >> 1) == h2) {
          const int cb = (w & 1) * 32;
#pragma unroll
          for (int mi = 0; mi < 4; ++mi)
#pragma unroll
            for (int ni = 0; ni < 2; ++ni) {
              f32x4 v = acc[mi][ni];
              int col = cb + ni * 16 + lrow;
              int rb = mi * 16 + quad * 4;
#pragma unroll
              for (int r = 0; r < 4; ++r) zb[(rb + r) * 68 + col] = v[r];
            }
        }
        __syncthreads();
#pragma unroll
        for (int it = 0; it < 4; ++it) {
          int idx = it * 256 + tid;
          int row = idx >> 4, jl = idx & 15;
          float4 z4 = *(float4*)&zb[row * 68 + jl * 4];
          float4 bi = *(const float4*)&biasp[n0 + h2 * 64 + jl * 4];
          int j = h2 * 16 + jl;
          int jg = jbase + j;
          int rg = r0 + row;
          float gi = sigmoidf_(z4.x + bi.x);
          float gf = sigmoidf_(z4.y + bi.y);
          float gg = tanhf_(z4.z + bi.z);
          float go = sigmoidf_(z4.w + bi.w);
          float cold = cl[row * 33 + j];
          float cnew = gf * cold + gi * gg;
          float hnew = go * tanhf_(cnew);
          cl[row * 33 + j] = cnew;
          __hip_bfloat16 hbf = __float2bfloat16(hnew);
          hnext[(size_t)rg * HIDDEN + jg] = hbf;
          if (t == PREV - 1) {
            // fork: replicate state into fake-half rows
            hnext[(size_t)(rg + BATCH) * HIDDEN + jg] = hbf;
            cbuf[(size_t)(rg + BATCH) * HIDDEN + jg] = cnew;
          }
          if (t >= PREV) {
            float p = hnew * w2[jg];
#pragma unroll
            for (int off = 8; off > 0; off >>= 1) p += __shfl_down(p, off, 16);
            if ((tid & 15) == 0) atomicAdd(&accout[rg * PRED + kout], p);
          }
        }
        __syncthreads();
      }
    }

    // ---- grid barrier (monotone phase, agent scope) ----
    if (t < TSTEPS - 1) {
      __syncthreads();
      if (tid == 0) {
        __threadfence();
        unsigned ph = (unsigned)(t + 1);
        unsigned old = __hip_atomic_fetch_add(cnt, 1u, __ATOMIC_ACQ_REL, __HIP_MEMORY_SCOPE_AGENT);
        if (old == NBLK - 1) {
          __hip_atomic_store(cnt, 0u, __ATOMIC_RELAXED, __HIP_MEMORY_SCOPE_AGENT);
          __hip_atomic_store(flag, ph, __ATOMIC_RELEASE, __HIP_MEMORY_SCOPE_AGENT);
        } else {
          while (__hip_atomic_load(flag, __ATOMIC_ACQUIRE, __HIP_MEMORY_SCOPE_AGENT) < ph)
            __builtin_amdgcn_s_sleep(2);
        }
        __threadfence();
      }
      __syncthreads();
    }
  }
}

// ---- final tanh chain over the 40960 fused dots ----
__global__ void final_kernel(const float* __restrict__ accout, const float* __restrict__ b2,
                             const float* __restrict__ w3, const float* __restrict__ b3,
                             const float* __restrict__ w4, const float* __restrict__ b4,
                             float* __restrict__ out) {
  int i = blockIdx.x * 256 + threadIdx.x;
  const int half = BATCH * PRED;
  if (i >= 2 * half) return;
  int r, k;
  if (i < half) {
    r = i / PRED;
    k = i % PRED;
  } else {
    r = BATCH + (i - half) / PRED;
    k = (i - half) % PRED;
  }
  float x = tanhf_(accout[r * PRED + k] + b2[0]);
  x = tanhf_(x * w3[0] + b3[0]);
  x = tanhf_(x * w4[0] + b4[0]);
  out[i] = x;
}

extern "C" void kernel_launch(void* const* d_in, const int* in_sizes, int n_in,
                              void* d_out, int out_size, void* d_ws, size_t ws_size,
                              hipStream_t stream) {
  const float* real_input = (const float*)d_in[0];
  const float* fake_input = (const float*)d_in[1];
  const float* Wx = (const float*)d_in[2];
  const float* Wh = (const float*)d_in[3];
  const float* b  = (const float*)d_in[4];
  const float* w2 = (const float*)d_in[5];
  const float* b2 = (const float*)d_in[6];
  const float* w3 = (const float*)d_in[7];
  const float* b3 = (const float*)d_in[8];
  const float* w4 = (const float*)d_in[9];
  const float* b4 = (const float*)d_in[10];
  float* out = (float*)d_out;

  char* ws = (char*)d_ws;
  size_t off = 0;
  __hip_bfloat16* WpT = (__hip_bfloat16*)(ws + off);  off += (size_t)N4H * KTOT * 2;
  float* biasp = (float*)(ws + off);                  off += (size_t)N4H * 4;
  __hip_bfloat16* xrb = (__hip_bfloat16*)(ws + off);  off += (size_t)BATCH * TSTEPS * FEAT * 2;
  __hip_bfloat16* xfb = (__hip_bfloat16*)(ws + off);  off += (size_t)BATCH * PRED * FEAT * 2;
  __hip_bfloat16* hb0 = (__hip_bfloat16*)(ws + off);  off += (size_t)2 * BATCH * HIDDEN * 2;
  __hip_bfloat16* hb1 = (__hip_bfloat16*)(ws + off);  off += (size_t)2 * BATCH * HIDDEN * 2;
  float* cbuf = (float*)(ws + off);                   off += (size_t)2 * BATCH * HIDDEN * 4;
  float* accout = (float*)(ws + off);                 off += (size_t)2 * BATCH * PRED * 4;
  unsigned* bar = (unsigned*)(ws + off);              off += 256;

  hipMemsetAsync(hb0, 0, (size_t)2 * BATCH * HIDDEN * 2, stream);
  hipMemsetAsync(accout, 0, (size_t)2 * BATCH * PRED * 4, stream);
  hipMemsetAsync(bar, 0, 256, stream);

  pack_w_kernel<<<dim3(KTOT / 64, N4H / 64), 256, 0, stream>>>(Wx, Wh, WpT);
  pack_bias_kernel<<<N4H / 256, 256, 0, stream>>>(b, biasp);
  {
    int n4 = BATCH * TSTEPS * FEAT / 4 + BATCH * PRED * FEAT / 4;
    cvt_x_kernel<<<(n4 + 255) / 256, 256, 0, stream>>>(real_input, fake_input, xrb, xfb);
  }

  {
    const __hip_bfloat16* a_xrb = xrb;
    const __hip_bfloat16* a_xfb = xfb;
    const __hip_bfloat16* a_WpT = WpT;
    const float* a_biasp = biasp;
    const float* a_w2 = w2;
    __hip_bfloat16* a_hb0 = hb0;
    __hip_bfloat16* a_hb1 = hb1;
    float* a_cbuf = cbuf;
    float* a_acc = accout;
    unsigned* a_bar = bar;
    void* args[10] = {&a_xrb, &a_xfb, &a_WpT, &a_biasp, &a_w2,
                      &a_hb0, &a_hb1, &a_cbuf, &a_acc, &a_bar};
    hipError_t e = hipLaunchCooperativeKernel((const void*)lstm_persistent,
                                              dim3(NBLK), dim3(256), args, 0, stream);
    if (e != hipSuccess) {
      // co-residency fallback: 1024 blocks at 33 KB LDS / <=128 VGPR are 4/CU resident
      lstm_persistent<<<dim3(NBLK), dim3(256), 0, stream>>>(
          xrb, xfb, WpT, biasp, w2, hb0, hb1, cbuf, accout, bar);
    }
  }

  final_kernel<<<(2 * BATCH * PRED + 255) / 256, 256, 0, stream>>>(accout, b2, w3, b3, w4, b4, out);
}

// Round 3
// 2675.975 us; speedup vs baseline: 2.2013x; 2.2013x over previous
//
#include <hip/hip_runtime.h>
#include <hip/hip_bf16.h>
#include <stdint.h>

#define HIDDEN 1024
#define FEAT   512
#define PREV   10
#define PRED   20
#define BATCH  1024
#define KTOT   (HIDDEN + FEAT)   // 1536
#define N4H    4096
#define TSTEPS (PREV + PRED)     // 30
#define NBLK   1024              // persistent grid: 4 blocks/CU on 256 CUs

typedef __attribute__((ext_vector_type(8))) short short8;
typedef __attribute__((ext_vector_type(4))) float f32x4;

// ---- async global->LDS 16B copy (wave-uniform LDS base + lane*16) ----
typedef __attribute__((address_space(3))) unsigned int u32_lds;
typedef const __attribute__((address_space(1))) unsigned int u32_gbl;

__device__ __forceinline__ void async16(void* lds, const void* g) {
  u32_lds* lp = (u32_lds*)(unsigned int)(uintptr_t)lds;
  u32_gbl* gp = (u32_gbl*)(uintptr_t)g;
  __builtin_amdgcn_global_load_lds(gp, lp, 16, 0, 0);
}

__device__ __forceinline__ float sigmoidf_(float x) {
  return 1.0f / (1.0f + __expf(-x));
}
__device__ __forceinline__ float tanhf_(float x) {
  return 1.0f - 2.0f / (1.0f + __expf(2.0f * x));
}

// ---- pack [Wh;Wx] (fp32, [K,4096] gate-blocked) -> WpT (bf16, [4096,K], gate-interleaved n=4j+g) ----
__global__ void pack_w_kernel(const float* __restrict__ Wx, const float* __restrict__ Wh,
                              __hip_bfloat16* __restrict__ WpT) {
  __shared__ float tile[64][65];
  const int k0 = blockIdx.x * 64, n0 = blockIdx.y * 64;
  const int tid = threadIdx.x;
  const float* src = (k0 < HIDDEN) ? (Wh + (size_t)k0 * N4H) : (Wx + (size_t)(k0 - HIDDEN) * N4H);
  {
    const int jl = tid & 15, g = (tid >> 4) & 3, klb = tid >> 6;
#pragma unroll
    for (int it = 0; it < 16; ++it) {
      int kl = klb + it * 4;
      tile[kl][4 * jl + g] = src[(size_t)kl * N4H + g * HIDDEN + (n0 >> 2) + jl];
    }
  }
  __syncthreads();
  {
    const int kl = tid & 63, nlb = tid >> 6;
#pragma unroll
    for (int it = 0; it < 16; ++it) {
      int nl = nlb + it * 4;
      WpT[(size_t)(n0 + nl) * KTOT + k0 + kl] = __float2bfloat16(tile[kl][nl]);
    }
  }
}

__global__ void pack_bias_kernel(const float* __restrict__ b, float* __restrict__ bp) {
  int n = blockIdx.x * 256 + threadIdx.x;
  if (n < N4H) bp[n] = b[(n & 3) * HIDDEN + (n >> 2)];
}

// ---- convert inputs fp32 -> bf16 ----
__global__ void cvt_x_kernel(const float* __restrict__ xr, const float* __restrict__ xf,
                             __hip_bfloat16* __restrict__ xrb, __hip_bfloat16* __restrict__ xfb) {
  const int NR4 = BATCH * TSTEPS * FEAT / 4;
  const int NF4 = BATCH * PRED * FEAT / 4;
  int i = blockIdx.x * 256 + threadIdx.x;
  float4 v;
  __hip_bfloat16* dst;
  if (i < NR4) {
    v = ((const float4*)xr)[i];
    dst = xrb + (size_t)i * 4;
  } else {
    int j = i - NR4;
    if (j >= NF4) return;
    v = ((const float4*)xf)[j];
    dst = xfb + (size_t)j * 4;
  }
  dst[0] = __float2bfloat16(v.x);
  dst[1] = __float2bfloat16(v.y);
  dst[2] = __float2bfloat16(v.z);
  dst[3] = __float2bfloat16(v.w);
}

// ---- one timestep tile: MT x 128 GEMM + fused gates. MT=32 (prefix) or 64 (main) ----
template <int MT>
__device__ __forceinline__ void do_step(
    const __hip_bfloat16* __restrict__ hcur, __hip_bfloat16* __restrict__ hnext,
    const __hip_bfloat16* __restrict__ xrb, const __hip_bfloat16* __restrict__ xfb,
    const __hip_bfloat16* __restrict__ bbase0, const float* __restrict__ biasp,
    const float* __restrict__ w2, float* __restrict__ cbuf, float* __restrict__ accout,
    float* cl, char* smA, char* smB,
    int t, int r0, int n0, int jbase,
    int tid, int w, int sub, int csrc, int quad, int lrow) {
  f32x4 acc[MT / 16][2];
#pragma unroll
  for (int a = 0; a < MT / 16; ++a)
#pragma unroll
    for (int b_ = 0; b_ < 2; ++b_) acc[a][b_] = (f32x4){0.f, 0.f, 0.f, 0.f};

#pragma unroll 1
  for (int kt = 0; kt < KTOT / 64; ++kt) {
    const int k0 = kt * 64;
    const __hip_bfloat16* abase;
    int astr;
    if (k0 < HIDDEN) {
      abase = hcur + (size_t)r0 * HIDDEN + k0;
      astr = HIDDEN;
    } else if (r0 < BATCH) {
      abase = xrb + ((size_t)r0 * TSTEPS + t) * FEAT + (k0 - HIDDEN);
      astr = TSTEPS * FEAT;
    } else {
      abase = xfb + ((size_t)(r0 - BATCH) * PRED + (t - PREV)) * FEAT + (k0 - HIDDEN);
      astr = PRED * FEAT;
    }
#pragma unroll
    for (int it = 0; it < MT / 32; ++it)
      async16(smA + (it * 32 + w * 8) * 128,
              abase + (size_t)(it * 32 + w * 8 + sub) * astr + csrc * 8);
    const __hip_bfloat16* bb = bbase0 + k0;
#pragma unroll
    for (int it = 0; it < 4; ++it)
      async16(smB + (it * 32 + w * 8) * 128,
              bb + (size_t)(it * 32 + w * 8 + sub) * KTOT + csrc * 8);
    __syncthreads();
#pragma unroll
    for (int kk = 0; kk < 2; ++kk) {
      const int swz = (((kk << 2) + quad) ^ (lrow & 7)) * 16;
      short8 af[MT / 16], bf[2];
#pragma unroll
      for (int mi = 0; mi < MT / 16; ++mi)
        af[mi] = *(const short8*)(smA + (mi * 16 + lrow) * 128 + swz);
#pragma unroll
      for (int ni = 0; ni < 2; ++ni)
        bf[ni] = *(const short8*)(smB + (w * 32 + ni * 16 + lrow) * 128 + swz);
#pragma unroll
      for (int mi = 0; mi < MT / 16; ++mi)
#pragma unroll
        for (int ni = 0; ni < 2; ++ni)
          acc[mi][ni] = __builtin_amdgcn_mfma_f32_16x16x32_bf16(af[mi], bf[ni], acc[mi][ni], 0, 0, 0);
    }
    __syncthreads();
  }

  const int kout = t - PREV;
  if (MT == 32) {
    // ---- single-pass epilogue: z 32x128 f32, stride 132, overlays staging LDS ----
    float* zb = (float*)smA;
#pragma unroll
    for (int mi = 0; mi < MT / 16; ++mi)
#pragma unroll
      for (int ni = 0; ni < 2; ++ni) {
        f32x4 v = acc[mi][ni];
        int col = w * 32 + ni * 16 + lrow;
        int rb = mi * 16 + quad * 4;
#pragma unroll
        for (int r = 0; r < 4; ++r) zb[(rb + r) * 132 + col] = v[r];
      }
    __syncthreads();
#pragma unroll
    for (int it = 0; it < 4; ++it) {
      int idx = it * 256 + tid;
      int row = idx >> 5, j = idx & 31;
      float4 z4 = *(float4*)&zb[row * 132 + j * 4];
      float4 bi = *(const float4*)&biasp[n0 + j * 4];
      float gi = sigmoidf_(z4.x + bi.x);
      float gf = sigmoidf_(z4.y + bi.y);
      float gg = tanhf_(z4.z + bi.z);
      float go = sigmoidf_(z4.w + bi.w);
      float cold = cl[row * 33 + j];
      float cnew = gf * cold + gi * gg;
      float hnew = go * tanhf_(cnew);
      cl[row * 33 + j] = cnew;
      int rg = r0 + row, jg = jbase + j;
      __hip_bfloat16 hbf = __float2bfloat16(hnew);
      hnext[(size_t)rg * HIDDEN + jg] = hbf;
      if (t == PREV - 1) {
        hnext[(size_t)(rg + BATCH) * HIDDEN + jg] = hbf;
        cbuf[(size_t)rg * HIDDEN + jg] = cnew;
        cbuf[(size_t)(rg + BATCH) * HIDDEN + jg] = cnew;
      }
    }
  } else {
    // ---- two-half epilogue: z 64x64 f32 per half, stride 68 ----
    float* zb = (float*)smA;
#pragma unroll 1
    for (int h2 = 0; h2 < 2; ++h2) {
      if ((w >> 1) == h2) {
        const int cb = (w & 1) * 32;
#pragma unroll
        for (int mi = 0; mi < MT / 16; ++mi)
#pragma unroll
          for (int ni = 0; ni < 2; ++ni) {
            f32x4 v = acc[mi][ni];
            int col = cb + ni * 16 + lrow;
            int rb = mi * 16 + quad * 4;
#pragma unroll
            for (int r = 0; r < 4; ++r) zb[(rb + r) * 68 + col] = v[r];
          }
      }
      __syncthreads();
#pragma unroll
      for (int it = 0; it < 4; ++it) {
        int idx = it * 256 + tid;
        int row = idx >> 4, jl = idx & 15;
        float4 z4 = *(float4*)&zb[row * 68 + jl * 4];
        float4 bi = *(const float4*)&biasp[n0 + h2 * 64 + jl * 4];
        int j = h2 * 16 + jl;
        int jg = jbase + j;
        int rg = r0 + row;
        float gi = sigmoidf_(z4.x + bi.x);
        float gf = sigmoidf_(z4.y + bi.y);
        float gg = tanhf_(z4.z + bi.z);
        float go = sigmoidf_(z4.w + bi.w);
        float cold = cl[row * 33 + j];
        float cnew = gf * cold + gi * gg;
        float hnew = go * tanhf_(cnew);
        cl[row * 33 + j] = cnew;
        hnext[(size_t)rg * HIDDEN + jg] = __float2bfloat16(hnew);
        float p = hnew * w2[jg];
#pragma unroll
        for (int off = 8; off > 0; off >>= 1) p += __shfl_down(p, off, 16);
        if ((tid & 15) == 0) atomicAdd(&accout[rg * PRED + kout], p);
      }
      __syncthreads();
    }
  }
}

// ---- persistent LSTM: all 30 steps in one cooperative dispatch ----
// Prefix (t<10): 32-row tiles, all 1024 blocks active. Main (t>=10): 64-row tiles.
// Cell state in LDS; handoff through cbuf at the t=9 -> t=10 boundary.
__global__ __launch_bounds__(256, 4)
void lstm_persistent(const __hip_bfloat16* __restrict__ xrb,
                     const __hip_bfloat16* __restrict__ xfb,
                     const __hip_bfloat16* __restrict__ WpT,
                     const float* __restrict__ biasp,
                     const float* __restrict__ w2,
                     __hip_bfloat16* __restrict__ hb0,
                     __hip_bfloat16* __restrict__ hb1,
                     float* __restrict__ cbuf,
                     float* __restrict__ accout,
                     unsigned* __restrict__ bar) {
  __shared__ __align__(16) char smem[24576];  // A stage 8K | B stage 16K ; z-epilogue overlays
  __shared__ float cl[64 * 33];               // cell state, stride 33
  char* smA = smem;
  char* smB = smem + 8192;

  const int tid = threadIdx.x;
  const int bid = blockIdx.x;
  const int nt = bid & 31, rt = bid >> 5;
  const int n0 = nt * 128;
  const int w = tid >> 6, l = tid & 63;
  const int sub = l >> 3;
  const int csrc = (l & 7) ^ sub;   // XOR-swizzled 16B source column
  const int quad = l >> 4, lrow = l & 15;
  const int jbase = nt * 32;
  unsigned* cnt = bar;
  unsigned* flag = bar + 32;        // separate cache line

  const __hip_bfloat16* bbase0 = WpT + (size_t)n0 * KTOT;

  for (int i = tid; i < 2048; i += 256) cl[(i >> 5) * 33 + (i & 31)] = 0.f;
  __syncthreads();

#pragma unroll 1
  for (int t = 0; t < TSTEPS; ++t) {
    const __hip_bfloat16* hcur = (t & 1) ? hb1 : hb0;
    __hip_bfloat16* hnext = (t & 1) ? hb0 : hb1;

    if (t < PREV) {
      do_step<32>(hcur, hnext, xrb, xfb, bbase0, biasp, w2, cbuf, accout,
                  cl, smA, smB, t, rt * 32, n0, jbase, tid, w, sub, csrc, quad, lrow);
    } else {
      if (t == PREV) {
        // re-load cell state for 64-row main ownership (written at t=9, ordered by barrier)
        const int r0m = rt * 64;
        for (int i = tid; i < 2048; i += 256)
          cl[(i >> 5) * 33 + (i & 31)] = cbuf[(size_t)(r0m + (i >> 5)) * HIDDEN + jbase + (i & 31)];
        __syncthreads();
      }
      do_step<64>(hcur, hnext, xrb, xfb, bbase0, biasp, w2, cbuf, accout,
                  cl, smA, smB, t, rt * 64, n0, jbase, tid, w, sub, csrc, quad, lrow);
    }

    // ---- grid barrier: relaxed poll, single acquire fence on exit ----
    if (t < TSTEPS - 1) {
      __syncthreads();
      if (tid == 0) {
        __builtin_amdgcn_fence(__ATOMIC_RELEASE, "agent");
        unsigned ph = (unsigned)(t + 1);
        unsigned old = __hip_atomic_fetch_add(cnt, 1u, __ATOMIC_ACQ_REL, __HIP_MEMORY_SCOPE_AGENT);
        if (old == NBLK - 1) {
          __hip_atomic_store(cnt, 0u, __ATOMIC_RELAXED, __HIP_MEMORY_SCOPE_AGENT);
          __hip_atomic_store(flag, ph, __ATOMIC_RELEASE, __HIP_MEMORY_SCOPE_AGENT);
        } else {
          while (__hip_atomic_load(flag, __ATOMIC_RELAXED, __HIP_MEMORY_SCOPE_AGENT) < ph)
            __builtin_amdgcn_s_sleep(8);
        }
        __builtin_amdgcn_fence(__ATOMIC_ACQUIRE, "agent");
      }
      __syncthreads();
    }
  }
}

// ---- final tanh chain over the 40960 fused dots ----
__global__ void final_kernel(const float* __restrict__ accout, const float* __restrict__ b2,
                             const float* __restrict__ w3, const float* __restrict__ b3,
                             const float* __restrict__ w4, const float* __restrict__ b4,
                             float* __restrict__ out) {
  int i = blockIdx.x * 256 + threadIdx.x;
  const int half = BATCH * PRED;
  if (i >= 2 * half) return;
  int r, k;
  if (i < half) {
    r = i / PRED;
    k = i % PRED;
  } else {
    r = BATCH + (i - half) / PRED;
    k = (i - half) % PRED;
  }
  float x = tanhf_(accout[r * PRED + k] + b2[0]);
  x = tanhf_(x * w3[0] + b3[0]);
  x = tanhf_(x * w4[0] + b4[0]);
  out[i] = x;
}

extern "C" void kernel_launch(void* const* d_in, const int* in_sizes, int n_in,
                              void* d_out, int out_size, void* d_ws, size_t ws_size,
                              hipStream_t stream) {
  const float* real_input = (const float*)d_in[0];
  const float* fake_input = (const float*)d_in[1];
  const float* Wx = (const float*)d_in[2];
  const float* Wh = (const float*)d_in[3];
  const float* b  = (const float*)d_in[4];
  const float* w2 = (const float*)d_in[5];
  const float* b2 = (const float*)d_in[6];
  const float* w3 = (const float*)d_in[7];
  const float* b3 = (const float*)d_in[8];
  const float* w4 = (const float*)d_in[9];
  const float* b4 = (const float*)d_in[10];
  float* out = (float*)d_out;

  char* ws = (char*)d_ws;
  size_t off = 0;
  __hip_bfloat16* WpT = (__hip_bfloat16*)(ws + off);  off += (size_t)N4H * KTOT * 2;
  float* biasp = (float*)(ws + off);                  off += (size_t)N4H * 4;
  __hip_bfloat16* xrb = (__hip_bfloat16*)(ws + off);  off += (size_t)BATCH * TSTEPS * FEAT * 2;
  __hip_bfloat16* xfb = (__hip_bfloat16*)(ws + off);  off += (size_t)BATCH * PRED * FEAT * 2;
  __hip_bfloat16* hb0 = (__hip_bfloat16*)(ws + off);  off += (size_t)2 * BATCH * HIDDEN * 2;
  __hip_bfloat16* hb1 = (__hip_bfloat16*)(ws + off);  off += (size_t)2 * BATCH * HIDDEN * 2;
  float* cbuf = (float*)(ws + off);                   off += (size_t)2 * BATCH * HIDDEN * 4;
  float* accout = (float*)(ws + off);                 off += (size_t)2 * BATCH * PRED * 4;
  unsigned* bar = (unsigned*)(ws + off);              off += 256;

  hipMemsetAsync(hb0, 0, (size_t)2 * BATCH * HIDDEN * 2, stream);
  hipMemsetAsync(accout, 0, (size_t)2 * BATCH * PRED * 4, stream);
  hipMemsetAsync(bar, 0, 256, stream);

  pack_w_kernel<<<dim3(KTOT / 64, N4H / 64), 256, 0, stream>>>(Wx, Wh, WpT);
  pack_bias_kernel<<<N4H / 256, 256, 0, stream>>>(b, biasp);
  {
    int n4 = BATCH * TSTEPS * FEAT / 4 + BATCH * PRED * FEAT / 4;
    cvt_x_kernel<<<(n4 + 255) / 256, 256, 0, stream>>>(real_input, fake_input, xrb, xfb);
  }

  {
    const __hip_bfloat16* a_xrb = xrb;
    const __hip_bfloat16* a_xfb = xfb;
    const __hip_bfloat16* a_WpT = WpT;
    const float* a_biasp = biasp;
    const float* a_w2 = w2;
    __hip_bfloat16* a_hb0 = hb0;
    __hip_bfloat16* a_hb1 = hb1;
    float* a_cbuf = cbuf;
    float* a_acc = accout;
    unsigned* a_bar = bar;
    void* args[10] = {&a_xrb, &a_xfb, &a_WpT, &a_biasp, &a_w2,
                      &a_hb0, &a_hb1, &a_cbuf, &a_acc, &a_bar};
    hipError_t e = hipLaunchCooperativeKernel((const void*)lstm_persistent,
                                              dim3(NBLK), dim3(256), args, 0, stream);
    if (e != hipSuccess) {
      // co-residency fallback: 1024 blocks at 33 KB LDS / 64 VGPR are 4/CU resident
      lstm_persistent<<<dim3(NBLK), dim3(256), 0, stream>>>(
          xrb, xfb, WpT, biasp, w2, hb0, hb1, cbuf, accout, bar);
    }
  }

  final_kernel<<<(2 * BATCH * PRED + 255) / 256, 256, 0, stream>>>(accout, b2, w3, b3, w4, b4, out);
}

// Round 4
// 1307.091 us; speedup vs baseline: 4.5068x; 2.0473x over previous
//
#include <hip/hip_runtime.h>
#include <hip/hip_bf16.h>
#include <stdint.h>
#include <string.h>

#define HIDDEN 1024
#define FEAT   512
#define PREV   10
#define PRED   20
#define BATCH  1024
#define KTOT   (HIDDEN + FEAT)   // 1536
#define N4H    4096
#define TSTEPS (PREV + PRED)     // 30
#define NBLK   512               // 2 blocks/CU on 256 CUs
#define NTHR   512

typedef __attribute__((ext_vector_type(8))) short short8;
typedef __attribute__((ext_vector_type(4))) float f32x4;
typedef unsigned long long ull;

// ---- async global->LDS 16B copy (wave-uniform LDS base + lane*16), plain-cached ----
typedef __attribute__((address_space(3))) unsigned int u32_lds;
typedef const __attribute__((address_space(1))) unsigned int u32_gbl;

__device__ __forceinline__ void async16(void* lds, const void* g) {
  u32_lds* lp = (u32_lds*)(unsigned int)(uintptr_t)lds;
  u32_gbl* gp = (u32_gbl*)(uintptr_t)g;
  __builtin_amdgcn_global_load_lds(gp, lp, 16, 0, 0);
}

__device__ __forceinline__ float sigmoidf_(float x) {
  return 1.0f / (1.0f + __expf(-x));
}
__device__ __forceinline__ float tanhf_(float x) {
  return 1.0f - 2.0f / (1.0f + __expf(2.0f * x));
}

// device-coherent (LLC) 8B load/store — bypass the non-coherent L1/L2
__device__ __forceinline__ ull cload(const void* p) {
  return __hip_atomic_load((const ull*)p, __ATOMIC_RELAXED, __HIP_MEMORY_SCOPE_AGENT);
}
__device__ __forceinline__ void cstore(void* p, ull v) {
  __hip_atomic_store((ull*)p, v, __ATOMIC_RELAXED, __HIP_MEMORY_SCOPE_AGENT);
}

// ---- pack [Wh;Wx] (fp32, [K,4096] gate-blocked) -> WpT (bf16, [4096,K], gate-interleaved n=4j+g) ----
__global__ void pack_w_kernel(const float* __restrict__ Wx, const float* __restrict__ Wh,
                              __hip_bfloat16* __restrict__ WpT) {
  __shared__ float tile[64][65];
  const int k0 = blockIdx.x * 64, n0 = blockIdx.y * 64;
  const int tid = threadIdx.x;
  const float* src = (k0 < HIDDEN) ? (Wh + (size_t)k0 * N4H) : (Wx + (size_t)(k0 - HIDDEN) * N4H);
  {
    const int jl = tid & 15, g = (tid >> 4) & 3, klb = tid >> 6;
#pragma unroll
    for (int it = 0; it < 16; ++it) {
      int kl = klb + it * 4;
      tile[kl][4 * jl + g] = src[(size_t)kl * N4H + g * HIDDEN + (n0 >> 2) + jl];
    }
  }
  __syncthreads();
  {
    const int kl = tid & 63, nlb = tid >> 6;
#pragma unroll
    for (int it = 0; it < 16; ++it) {
      int nl = nlb + it * 4;
      WpT[(size_t)(n0 + nl) * KTOT + k0 + kl] = __float2bfloat16(tile[kl][nl]);
    }
  }
}

__global__ void pack_bias_kernel(const float* __restrict__ b, float* __restrict__ bp) {
  int n = blockIdx.x * 256 + threadIdx.x;
  if (n < N4H) bp[n] = b[(n & 3) * HIDDEN + (n >> 2)];
}

// ---- convert inputs fp32 -> bf16 ----
__global__ void cvt_x_kernel(const float* __restrict__ xr, const float* __restrict__ xf,
                             __hip_bfloat16* __restrict__ xrb, __hip_bfloat16* __restrict__ xfb) {
  const int NR4 = BATCH * TSTEPS * FEAT / 4;
  const int NF4 = BATCH * PRED * FEAT / 4;
  int i = blockIdx.x * 256 + threadIdx.x;
  float4 v;
  __hip_bfloat16* dst;
  if (i < NR4) {
    v = ((const float4*)xr)[i];
    dst = xrb + (size_t)i * 4;
  } else {
    int j = i - NR4;
    if (j >= NF4) return;
    v = ((const float4*)xf)[j];
    dst = xfb + (size_t)j * 4;
  }
  dst[0] = __float2bfloat16(v.x);
  dst[1] = __float2bfloat16(v.y);
  dst[2] = __float2bfloat16(v.z);
  dst[3] = __float2bfloat16(v.w);
}

// ---- persistent LSTM, no cache-invalidating fences ----
// 512 blocks x 512 thr. nt = bid&15 (256 n-cols, weight slice L2-resident all 30
// steps), rt = bid>>4 (64 batch rows). h traffic via device-coherent (sc0 sc1)
// accesses only; weights/x plain-cached. Cell state in registers (8/thread).
__global__ __launch_bounds__(512, 4)
void lstm_persistent(const __hip_bfloat16* __restrict__ xrb,
                     const __hip_bfloat16* __restrict__ xfb,
                     const __hip_bfloat16* __restrict__ WpT,
                     const float* __restrict__ biasp,
                     const float* __restrict__ w2,
                     __hip_bfloat16* __restrict__ hb0,
                     __hip_bfloat16* __restrict__ hb1,
                     float* __restrict__ cbuf,
                     float* __restrict__ accout,
                     unsigned* __restrict__ bar) {
  __shared__ __align__(16) char smem[40960];  // smA 8K | smB 32K ; z-epilogue overlays (64x132 f32)
  char* smA = smem;
  char* smB = smem + 8192;

  const int tid = threadIdx.x;
  const int bid = blockIdx.x;
  const int nt = bid & 15, rt = bid >> 4;
  const int n0 = nt * 256;
  const int r0 = rt * 64;
  const int w = tid >> 6, l = tid & 63;
  const int sub = l >> 3;
  const int csrc = (l & 7) ^ sub;   // XOR-swizzled 16B source column
  const int quad = l >> 4, lrow = l & 15;
  const int wm = w & 1, wn = w >> 1;         // wave tile: rows wm*32+32, cols wn*64+64
  const int row_e = tid >> 3, jq = tid & 7;  // epilogue: 64 rows x 8 j-quads
  unsigned* cnt = bar;
  unsigned* flag = bar + 32;

  const unsigned short* wp_us = (const unsigned short*)WpT;
  float creg[8] = {0.f, 0.f, 0.f, 0.f, 0.f, 0.f, 0.f, 0.f};

#pragma unroll 1
  for (int t = 0; t < TSTEPS; ++t) {
    const unsigned short* hcur = (const unsigned short*)((t & 1) ? hb1 : hb0);
    unsigned short* hnext = (unsigned short*)((t & 1) ? hb0 : hb1);
    const bool active = (t >= PREV) || (rt < 16);

    if (active) {
      if (t == PREV && r0 >= BATCH) {
        // fork: pick up cell state written at t==9 by real-row owners (LLC-coherent)
#pragma unroll
        for (int h2 = 0; h2 < 2; ++h2) {
          size_t base = (size_t)(r0 - BATCH + row_e) * HIDDEN + nt * 64 + h2 * 32 + jq * 4;
          ull d0 = cload(&cbuf[base]);
          ull d1 = cload(&cbuf[base + 2]);
          float2 f0 = *(float2*)&d0, f1 = *(float2*)&d1;
          creg[h2 * 4 + 0] = f0.x;
          creg[h2 * 4 + 1] = f0.y;
          creg[h2 * 4 + 2] = f1.x;
          creg[h2 * 4 + 3] = f1.y;
        }
      }
      const int r0h = (t == PREV && r0 >= BATCH) ? (r0 - BATCH) : r0;

      f32x4 acc[2][4];
#pragma unroll
      for (int a = 0; a < 2; ++a)
#pragma unroll
        for (int b_ = 0; b_ < 4; ++b_) acc[a][b_] = (f32x4){0.f, 0.f, 0.f, 0.f};

#pragma unroll 1
      for (int kt = 0; kt < KTOT / 64; ++kt) {
        const int k0 = kt * 64;
        // --- B tile [256 n x 64 k], plain-cached (stays in L2 across steps) ---
        const unsigned short* bb = wp_us + (size_t)n0 * KTOT + k0;
#pragma unroll
        for (int it = 0; it < 4; ++it)
          async16(smB + (w * 32 + it * 8) * 128,
                  bb + (size_t)(w * 32 + it * 8 + sub) * KTOT + csrc * 8);
        // --- A tile [64 rows x 64 k] ---
        if (k0 < HIDDEN) {
          // h: device-coherent loads (bypass stale L1/L2), then LDS write
          const unsigned short* ap = hcur + (size_t)(r0h + w * 8 + sub) * HIDDEN + k0 + csrc * 8;
          ull d0 = cload(ap);
          ull d1 = cload(ap + 4);
          ull* lw = (ull*)(smA + (w * 8 + sub) * 128 + (l & 7) * 16);
          lw[0] = d0;
          lw[1] = d1;
        } else {
          const unsigned short* xb;
          size_t xstr;
          if (r0 < BATCH) {
            xb = (const unsigned short*)xrb + ((size_t)r0 * TSTEPS + t) * FEAT + (k0 - HIDDEN);
            xstr = TSTEPS * FEAT;
          } else {
            xb = (const unsigned short*)xfb + ((size_t)(r0 - BATCH) * PRED + (t - PREV)) * FEAT + (k0 - HIDDEN);
            xstr = PRED * FEAT;
          }
          async16(smA + (w * 8) * 128, xb + (size_t)(w * 8 + sub) * xstr + csrc * 8);
        }
        __syncthreads();
#pragma unroll
        for (int kk = 0; kk < 2; ++kk) {
          const int swz = (((kk << 2) + quad) ^ (lrow & 7)) * 16;
          short8 af[2], bf[4];
#pragma unroll
          for (int mi = 0; mi < 2; ++mi)
            af[mi] = *(const short8*)(smA + (wm * 32 + mi * 16 + lrow) * 128 + swz);
#pragma unroll
          for (int ni = 0; ni < 4; ++ni)
            bf[ni] = *(const short8*)(smB + (wn * 64 + ni * 16 + lrow) * 128 + swz);
#pragma unroll
          for (int mi = 0; mi < 2; ++mi)
#pragma unroll
            for (int ni = 0; ni < 4; ++ni)
              acc[mi][ni] = __builtin_amdgcn_mfma_f32_16x16x32_bf16(af[mi], bf[ni], acc[mi][ni], 0, 0, 0);
        }
        __syncthreads();
      }

      // ---- epilogue: two 128-col passes; z 64x132 f32 overlays staging LDS ----
      float* zb = (float*)smem;
      const int kout = t - PREV;
#pragma unroll 1
      for (int h2 = 0; h2 < 2; ++h2) {
        if ((wn >> 1) == h2) {
          const int cb = (wn & 1) * 64;
#pragma unroll
          for (int mi = 0; mi < 2; ++mi)
#pragma unroll
            for (int ni = 0; ni < 4; ++ni) {
              f32x4 v = acc[mi][ni];
              int col = cb + ni * 16 + lrow;
              int rb = wm * 32 + mi * 16 + quad * 4;
#pragma unroll
              for (int r = 0; r < 4; ++r) zb[(rb + r) * 132 + col] = v[r];
            }
        }
        __syncthreads();
        // gates: 64 rows x 32 j per pass; thread -> (row_e, j = jq*4+it)
        unsigned short hs[4];
        float cn[4];
        float psum = 0.f;
#pragma unroll
        for (int it = 0; it < 4; ++it) {
          int jloc = jq * 4 + it;
          float4 z4 = *(float4*)&zb[row_e * 132 + jloc * 4];
          float4 bi = *(const float4*)&biasp[n0 + h2 * 128 + jloc * 4];
          int jg = nt * 64 + h2 * 32 + jloc;
          float gi = sigmoidf_(z4.x + bi.x);
          float gf = sigmoidf_(z4.y + bi.y);
          float gg = tanhf_(z4.z + bi.z);
          float go = sigmoidf_(z4.w + bi.w);
          int ci = h2 * 4 + it;
          float cnew = gf * creg[ci] + gi * gg;
          float hnew = go * tanhf_(cnew);
          creg[ci] = cnew;
          cn[it] = cnew;
          __hip_bfloat16 hbv = __float2bfloat16(hnew);
          hs[it] = *(unsigned short*)&hbv;
          if (t >= PREV) psum += hnew * w2[jg];
        }
        const int rg = r0 + row_e;
        const int jg0 = nt * 64 + h2 * 32 + jq * 4;
        ull hpack;
        memcpy(&hpack, hs, 8);
        cstore(&hnext[(size_t)rg * HIDDEN + jg0], hpack);  // device-coherent h write
        if (t == PREV - 1) {
          ull c01, c23;
          memcpy(&c01, &cn[0], 8);
          memcpy(&c23, &cn[2], 8);
          cstore(&cbuf[(size_t)rg * HIDDEN + jg0], c01);
          cstore(&cbuf[(size_t)rg * HIDDEN + jg0 + 2], c23);
        }
        if (t >= PREV) {
          psum += __shfl_down(psum, 4, 8);
          psum += __shfl_down(psum, 2, 8);
          psum += __shfl_down(psum, 1, 8);
          if ((tid & 7) == 0) atomicAdd(&accout[rg * PRED + kout], psum);
        }
        __syncthreads();
      }
    }

    // ---- grid barrier: no fences (coherent data goes through LLC already) ----
    if (t < TSTEPS - 1) {
      __syncthreads();  // per-wave vmcnt(0) drain precedes s_barrier
      if (tid == 0) {
        unsigned ph = (unsigned)(t + 1);
        unsigned old = __hip_atomic_fetch_add(cnt, 1u, __ATOMIC_RELAXED, __HIP_MEMORY_SCOPE_AGENT);
        if (old == NBLK - 1) {
          __hip_atomic_store(cnt, 0u, __ATOMIC_RELAXED, __HIP_MEMORY_SCOPE_AGENT);
          __hip_atomic_store(flag, ph, __ATOMIC_RELAXED, __HIP_MEMORY_SCOPE_AGENT);
        } else {
          while (__hip_atomic_load(flag, __ATOMIC_RELAXED, __HIP_MEMORY_SCOPE_AGENT) < ph)
            __builtin_amdgcn_s_sleep(4);
        }
      }
      __syncthreads();
    }
  }
}

// ---- final tanh chain over the 40960 fused dots ----
__global__ void final_kernel(const float* __restrict__ accout, const float* __restrict__ b2,
                             const float* __restrict__ w3, const float* __restrict__ b3,
                             const float* __restrict__ w4, const float* __restrict__ b4,
                             float* __restrict__ out) {
  int i = blockIdx.x * 256 + threadIdx.x;
  const int half = BATCH * PRED;
  if (i >= 2 * half) return;
  int r, k;
  if (i < half) {
    r = i / PRED;
    k = i % PRED;
  } else {
    r = BATCH + (i - half) / PRED;
    k = (i - half) % PRED;
  }
  float x = tanhf_(accout[r * PRED + k] + b2[0]);
  x = tanhf_(x * w3[0] + b3[0]);
  x = tanhf_(x * w4[0] + b4[0]);
  out[i] = x;
}

extern "C" void kernel_launch(void* const* d_in, const int* in_sizes, int n_in,
                              void* d_out, int out_size, void* d_ws, size_t ws_size,
                              hipStream_t stream) {
  const float* real_input = (const float*)d_in[0];
  const float* fake_input = (const float*)d_in[1];
  const float* Wx = (const float*)d_in[2];
  const float* Wh = (const float*)d_in[3];
  const float* b  = (const float*)d_in[4];
  const float* w2 = (const float*)d_in[5];
  const float* b2 = (const float*)d_in[6];
  const float* w3 = (const float*)d_in[7];
  const float* b3 = (const float*)d_in[8];
  const float* w4 = (const float*)d_in[9];
  const float* b4 = (const float*)d_in[10];
  float* out = (float*)d_out;

  char* ws = (char*)d_ws;
  size_t off = 0;
  __hip_bfloat16* WpT = (__hip_bfloat16*)(ws + off);  off += (size_t)N4H * KTOT * 2;
  float* biasp = (float*)(ws + off);                  off += (size_t)N4H * 4;
  __hip_bfloat16* xrb = (__hip_bfloat16*)(ws + off);  off += (size_t)BATCH * TSTEPS * FEAT * 2;
  __hip_bfloat16* xfb = (__hip_bfloat16*)(ws + off);  off += (size_t)BATCH * PRED * FEAT * 2;
  __hip_bfloat16* hb0 = (__hip_bfloat16*)(ws + off);  off += (size_t)2 * BATCH * HIDDEN * 2;
  __hip_bfloat16* hb1 = (__hip_bfloat16*)(ws + off);  off += (size_t)2 * BATCH * HIDDEN * 2;
  float* cbuf = (float*)(ws + off);                   off += (size_t)BATCH * HIDDEN * 4;
  float* accout = (float*)(ws + off);                 off += (size_t)2 * BATCH * PRED * 4;
  unsigned* bar = (unsigned*)(ws + off);              off += 256;

  hipMemsetAsync(hb0, 0, (size_t)2 * BATCH * HIDDEN * 2, stream);
  hipMemsetAsync(accout, 0, (size_t)2 * BATCH * PRED * 4, stream);
  hipMemsetAsync(bar, 0, 256, stream);

  pack_w_kernel<<<dim3(KTOT / 64, N4H / 64), 256, 0, stream>>>(Wx, Wh, WpT);
  pack_bias_kernel<<<N4H / 256, 256, 0, stream>>>(b, biasp);
  {
    int n4 = BATCH * TSTEPS * FEAT / 4 + BATCH * PRED * FEAT / 4;
    cvt_x_kernel<<<(n4 + 255) / 256, 256, 0, stream>>>(real_input, fake_input, xrb, xfb);
  }

  {
    const __hip_bfloat16* a_xrb = xrb;
    const __hip_bfloat16* a_xfb = xfb;
    const __hip_bfloat16* a_WpT = WpT;
    const float* a_biasp = biasp;
    const float* a_w2 = w2;
    __hip_bfloat16* a_hb0 = hb0;
    __hip_bfloat16* a_hb1 = hb1;
    float* a_cbuf = cbuf;
    float* a_acc = accout;
    unsigned* a_bar = bar;
    void* args[10] = {&a_xrb, &a_xfb, &a_WpT, &a_biasp, &a_w2,
                      &a_hb0, &a_hb1, &a_cbuf, &a_acc, &a_bar};
    hipError_t e = hipLaunchCooperativeKernel((const void*)lstm_persistent,
                                              dim3(NBLK), dim3(NTHR), args, 0, stream);
    if (e != hipSuccess) {
      // co-residency fallback: 512 blocks at 40 KB LDS / <=128 VGPR are 2/CU resident
      lstm_persistent<<<dim3(NBLK), dim3(NTHR), 0, stream>>>(
          xrb, xfb, WpT, biasp, w2, hb0, hb1, cbuf, accout, bar);
    }
  }

  final_kernel<<<(2 * BATCH * PRED + 255) / 256, 256, 0, stream>>>(accout, b2, w3, b3, w4, b4, out);
}